// Round 5
// baseline (480.074 us; speedup 1.0000x reference)
//
#include <hip/hip_runtime.h>
#include <hip/hip_bf16.h>

#define N_NODES 100000
#define EDGES   1600000
#define D       128
#define NLAYERS 2
#define NEG_SLOPE 0.01f
#define NB ((N_NODES + 255) / 256)   // 391 scan blocks
#define VAL_SCALE 524288.0f          // 2^19: val in [0,1/16) -> q in [0,32767]
#define VAL_INV   (1.0f / 524288.0f)

typedef __attribute__((ext_vector_type(8))) __bf16 bf16x8;
typedef __attribute__((ext_vector_type(4))) float  f32x4;

__device__ __forceinline__ float bf_lo(unsigned u) { return __uint_as_float(u << 16); }
__device__ __forceinline__ float bf_hi(unsigned u) { return __uint_as_float(u & 0xffff0000u); }

// ---------------- CSR build step 1: row histogram
__global__ void hist_kernel(const int* __restrict__ arow, int* __restrict__ deg) {
    int e = blockIdx.x * 256 + threadIdx.x;
    if (e < EDGES) atomicAdd(&deg[arow[e]], 1);
}

// ---------------- CSR build step 2a: per-block reduce of deg
__global__ __launch_bounds__(256) void reduce_deg_kernel(const int* __restrict__ deg,
                                                         int* __restrict__ bsum) {
    __shared__ int sh[256];
    int t = threadIdx.x, i = blockIdx.x * 256 + t;
    sh[t] = (i < N_NODES) ? deg[i] : 0;
    __syncthreads();
    for (int off = 128; off > 0; off >>= 1) {
        if (t < off) sh[t] += sh[t + off];
        __syncthreads();
    }
    if (t == 0) bsum[blockIdx.x] = sh[0];
}

// ---------------- CSR build step 2b: single-block scan of 391 partials
__global__ __launch_bounds__(512) void scan_partials_kernel(const int* __restrict__ bsum,
                                                            int* __restrict__ boff,
                                                            int* __restrict__ rowptr) {
    __shared__ int sh[512];
    int t = threadIdx.x;
    int v = (t < NB) ? bsum[t] : 0;
    sh[t] = v;
    __syncthreads();
    for (int off = 1; off < 512; off <<= 1) {
        int u = (t >= off) ? sh[t - off] : 0;
        __syncthreads();
        sh[t] += u;
        __syncthreads();
    }
    if (t < NB) boff[t] = sh[t] - v;          // exclusive
    if (t == 0) rowptr[N_NODES] = sh[NB - 1]; // total == EDGES
}

// ---------------- CSR build step 2c: block-local scan + offset -> rowptr/cursor
__global__ __launch_bounds__(256) void scan_rows_kernel(const int* __restrict__ deg,
                                                        const int* __restrict__ boff,
                                                        int* __restrict__ rowptr,
                                                        int* __restrict__ cursor) {
    __shared__ int sh[256];
    int t = threadIdx.x, i = blockIdx.x * 256 + t;
    int d = (i < N_NODES) ? deg[i] : 0;
    sh[t] = d;
    __syncthreads();
    for (int off = 1; off < 256; off <<= 1) {
        int u = (t >= off) ? sh[t - off] : 0;
        __syncthreads();
        sh[t] += u;
        __syncthreads();
    }
    if (i < N_NODES) {
        int p = boff[blockIdx.x] + sh[t] - d;
        rowptr[i] = p;
        cursor[i] = p;
    }
}

// ---------------- CSR build step 3: scatter packed (col<<15 | q15(val)) u32
__global__ void scatter_kernel(const int* __restrict__ arow,
                               const int* __restrict__ acol,
                               const float* __restrict__ aval,
                               int*      __restrict__ cursor,
                               unsigned* __restrict__ cpack) {
    int e = blockIdx.x * 256 + threadIdx.x;
    if (e >= EDGES) return;
    int r = arow[e];
    int pos = atomicAdd(&cursor[r], 1);
    int q = (int)(aval[e] * VAL_SCALE);        // floor; val<1/16 -> q<=32767
    if (q > 32767) q = 32767;
    unsigned pk = ((unsigned)acol[e] << 15) | (unsigned)q;
    __builtin_nontemporal_store(pk, &cpack[pos]);
}

// ---------------- out slot0 = emb (f32) and ego_bf = bf16(emb), one read pass
__global__ void copy_emb_kernel(const float* __restrict__ emb,
                                float* __restrict__ out0,
                                __bf16* __restrict__ bf) {
    int t = blockIdx.x * 256 + threadIdx.x;   // N*D/8 threads
    if (t >= N_NODES * D / 8) return;
    const float4* p = (const float4*)emb + (size_t)t * 2;
    float4 a = p[0], b = p[1];
    ((float4*)out0)[(size_t)t * 2]     = a;
    ((float4*)out0)[(size_t)t * 2 + 1] = b;
    bf16x8 o;
    o[0] = (__bf16)a.x; o[1] = (__bf16)a.y; o[2] = (__bf16)a.z; o[3] = (__bf16)a.w;
    o[4] = (__bf16)b.x; o[5] = (__bf16)b.y; o[6] = (__bf16)b.z; o[7] = (__bf16)b.w;
    *((bf16x8*)bf + t) = o;
}

// ---------------- SpMM (CSR gather, bf16 ego, packed u32 edges): one wave per row
__global__ __launch_bounds__(256) void spmm_csr_kernel(
    const unsigned* __restrict__ ego_bf,   // N x D bf16 as uint pairs
    const int*      __restrict__ rowptr,
    const unsigned* __restrict__ cpack,
    float*          __restrict__ side) {
    int row  = blockIdx.x * 4 + (threadIdx.x >> 6);
    int lane = threadIdx.x & 63;
    if (row >= N_NODES) return;
    int beg = rowptr[row], end = rowptr[row + 1];
    float accx = 0.f, accy = 0.f;
    int e = beg;
    for (; e + 4 <= end; e += 4) {
        unsigned p0 = cpack[e], p1 = cpack[e + 1], p2 = cpack[e + 2], p3 = cpack[e + 3];
        unsigned u0 = ego_bf[(size_t)(p0 >> 15) * (D / 2) + lane];
        unsigned u1 = ego_bf[(size_t)(p1 >> 15) * (D / 2) + lane];
        unsigned u2 = ego_bf[(size_t)(p2 >> 15) * (D / 2) + lane];
        unsigned u3 = ego_bf[(size_t)(p3 >> 15) * (D / 2) + lane];
        float v0 = (float)(p0 & 0x7fffu) * VAL_INV;
        float v1 = (float)(p1 & 0x7fffu) * VAL_INV;
        float v2 = (float)(p2 & 0x7fffu) * VAL_INV;
        float v3 = (float)(p3 & 0x7fffu) * VAL_INV;
        accx += v0 * bf_lo(u0) + v1 * bf_lo(u1) + v2 * bf_lo(u2) + v3 * bf_lo(u3);
        accy += v0 * bf_hi(u0) + v1 * bf_hi(u1) + v2 * bf_hi(u2) + v3 * bf_hi(u3);
    }
    for (; e < end; e++) {
        unsigned p = cpack[e];
        unsigned u = ego_bf[(size_t)(p >> 15) * (D / 2) + lane];
        float v = (float)(p & 0x7fffu) * VAL_INV;
        accx += v * bf_lo(u);
        accy += v * bf_hi(u);
    }
    *((float2*)(side + (size_t)row * D) + lane) = make_float2(accx, accy);
}

// ---------------- Prepack W (both layers, both mats) into MFMA B-fragment order, bf16.
__global__ void prepack_kernel(const float* __restrict__ wsum,
                               const float* __restrict__ wprod,
                               __bf16*      __restrict__ wpk) {
    int t = blockIdx.x * blockDim.x + threadIdx.x;   // 65536 total
    int j     = t & 7;
    int lane  = (t >> 3) & 63;
    int cf    = (t >> 9) & 7;
    int kc    = (t >> 12) & 3;
    int mat   = (t >> 14) & 1;
    int layer = (t >> 15) & 1;
    int k   = kc * 32 + (lane >> 4) * 8 + j;
    int col = cf * 16 + (lane & 15);
    const float* W = mat ? wprod : wsum;
    wpk[t] = (__bf16)W[((size_t)layer * D + k) * D + col];
}

// ---------------- Fused dense + L2-normalize epilogue.
__global__ __launch_bounds__(256) void dense_kernel(
    const float*  __restrict__ ego,
    const float*  __restrict__ ego_scale,  // nullable: per-row un-normalize factor
    const float*  __restrict__ side,
    const bf16x8* __restrict__ wpk,        // this layer: 2048 sum frags, then 2048 prod
    const float*  __restrict__ bsum,
    const float*  __restrict__ bprod,
    float*        __restrict__ out_norm,
    float*        __restrict__ rn,         // nullable
    __bf16*       __restrict__ out_bf) {   // nullable
    int lane = threadIdx.x & 63;
    int wid  = threadIdx.x >> 6;
    int node_base = blockIdx.x * 64 + wid * 16;
    int arow_node = node_base + (lane & 15);   // A-frag row
    int kgrp = lane >> 4;

    f32x4 acc_s[8], acc_p[8];
#pragma unroll
    for (int i = 0; i < 8; i++) { acc_s[i] = (f32x4)(0.f); acc_p[i] = (f32x4)(0.f); }

    bool avalid = arow_node < N_NODES;
    const float* erow = ego  + (size_t)arow_node * D;
    const float* srow = side + (size_t)arow_node * D;
    float esc = (ego_scale && avalid) ? ego_scale[arow_node] : 1.0f;

#pragma unroll
    for (int kc = 0; kc < 4; kc++) {
        int kbase = kc * 32 + kgrp * 8;
        bf16x8 a_s, a_p;
        if (avalid) {
            float4 e0 = *(const float4*)(erow + kbase);
            float4 e1 = *(const float4*)(erow + kbase + 4);
            float4 s0 = *(const float4*)(srow + kbase);
            float4 s1 = *(const float4*)(srow + kbase + 4);
            float es[8] = {e0.x, e0.y, e0.z, e0.w, e1.x, e1.y, e1.z, e1.w};
            float ss[8] = {s0.x, s0.y, s0.z, s0.w, s1.x, s1.y, s1.z, s1.w};
#pragma unroll
            for (int j = 0; j < 8; j++) {
                float ev = es[j] * esc;
                a_s[j] = (__bf16)(ev + ss[j]);
                a_p[j] = (__bf16)(ev * ss[j]);
            }
        } else {
#pragma unroll
            for (int j = 0; j < 8; j++) { a_s[j] = (__bf16)0.f; a_p[j] = (__bf16)0.f; }
        }
#pragma unroll
        for (int cf = 0; cf < 8; cf++) {
            bf16x8 bs = wpk[(kc * 8 + cf) * 64 + lane];
            bf16x8 bp = wpk[2048 + (kc * 8 + cf) * 64 + lane];
            acc_s[cf] = __builtin_amdgcn_mfma_f32_16x16x32_bf16(a_s, bs, acc_s[cf], 0, 0, 0);
            acc_p[cf] = __builtin_amdgcn_mfma_f32_16x16x32_bf16(a_p, bp, acc_p[cf], 0, 0, 0);
        }
    }

    // epilogue: C/D layout col = lane&15, row = (lane>>4)*4 + reg
    int colb = lane & 15;
    float ssq[4] = {0.f, 0.f, 0.f, 0.f};
#pragma unroll
    for (int cf = 0; cf < 8; cf++) {
        int d = cf * 16 + colb;
        float bsv = bsum[d], bpv = bprod[d];
#pragma unroll
        for (int r = 0; r < 4; r++) {
            float ys = acc_s[cf][r] + bsv;
            float yp = acc_p[cf][r] + bpv;
            ys = ys >= 0.f ? ys : NEG_SLOPE * ys;
            yp = yp >= 0.f ? yp : NEG_SLOPE * yp;
            float y = ys + yp;
            acc_s[cf][r] = y;          // reuse acc_s as y storage
            ssq[r] += y * y;
        }
    }
#pragma unroll
    for (int r = 0; r < 4; r++) {
#pragma unroll
        for (int m = 1; m < 16; m <<= 1) ssq[r] += __shfl_xor(ssq[r], m);
    }
    float nrm[4], inv[4];
#pragma unroll
    for (int r = 0; r < 4; r++) {
        nrm[r] = fmaxf(sqrtf(ssq[r]), 1e-12f);
        inv[r] = 1.0f / nrm[r];
    }
#pragma unroll
    for (int cf = 0; cf < 8; cf++) {
        int d = cf * 16 + colb;
#pragma unroll
        for (int r = 0; r < 4; r++) {
            int node = node_base + kgrp * 4 + r;
            if (node < N_NODES) {
                float y = acc_s[cf][r];
                out_norm[(size_t)node * D + d] = y * inv[r];
                if (out_bf) out_bf[(size_t)node * D + d] = (__bf16)y;
            }
        }
    }
    if (rn && colb == 0) {
#pragma unroll
        for (int r = 0; r < 4; r++) {
            int node = node_base + kgrp * 4 + r;
            if (node < N_NODES) rn[node] = nrm[r];
        }
    }
}

extern "C" void kernel_launch(void* const* d_in, const int* in_sizes, int n_in,
                              void* d_out, int out_size, void* d_ws, size_t ws_size,
                              hipStream_t stream) {
    const float* emb   = (const float*)d_in[0];
    const int*   arow  = (const int*)d_in[1];
    const int*   acol  = (const int*)d_in[2];
    const float* aval  = (const float*)d_in[3];
    const float* wsum  = (const float*)d_in[4];
    const float* bsum  = (const float*)d_in[5];
    const float* wprod = (const float*)d_in[6];
    const float* bprod = (const float*)d_in[7];
    float* out = (float*)d_out;

    const size_t slot = (size_t)N_NODES * D;          // elements per [N,D] slab
    char* ws = (char*)d_ws;
    size_t off = 0;
    float*    side   = (float*)(ws + off); off += slot * 4;                 // 51.2 MB
    __bf16*   wpk    = (__bf16*)(ws + off); off += 65536 * 2;               // 128 KB
    int*      deg    = (int*)(ws + off); off += (size_t)N_NODES * 4;        // 400 KB
    int*      rowptr = (int*)(ws + off); off += ((size_t)N_NODES + 4) * 4;  // 400 KB
    int*      cursor = (int*)(ws + off); off += (size_t)N_NODES * 4;        // 400 KB
    unsigned* cpack  = (unsigned*)(ws + off); off += (size_t)EDGES * 4;     // 6.4 MB
    int*      bsumP  = (int*)(ws + off); off += (size_t)NB * 4;
    int*      boffP  = (int*)(ws + off); off += (size_t)NB * 4;
    float*    rn     = (float*)(ws + off); off += (size_t)N_NODES * 4;      // 400 KB

    // bf16 ego buffer aliased into out slot 2 (dead until dense layer-2 writes it;
    // all uses are stream-ordered strictly before that write)
    __bf16* ego_bf = (__bf16*)(out + 2 * slot);

    // ---- CSR build (once, reused by both layers)
    hipMemsetAsync(deg, 0, (size_t)N_NODES * 4, stream);
    hist_kernel<<<(EDGES + 255) / 256, 256, 0, stream>>>(arow, deg);
    reduce_deg_kernel<<<NB, 256, 0, stream>>>(deg, bsumP);
    scan_partials_kernel<<<1, 512, 0, stream>>>(bsumP, boffP, rowptr);
    scan_rows_kernel<<<NB, 256, 0, stream>>>(deg, boffP, rowptr, cursor);
    scatter_kernel<<<(EDGES + 255) / 256, 256, 0, stream>>>(arow, acol, aval, cursor, cpack);

    // out slot 0 = embeddings (f32) + bf16 ego for layer-1 spmm, one pass
    copy_emb_kernel<<<(N_NODES * D / 8 + 255) / 256, 256, 0, stream>>>(emb, out, ego_bf);

    prepack_kernel<<<65536 / 256, 256, 0, stream>>>(wsum, wprod, wpk);

    // ---- layer 1
    spmm_csr_kernel<<<(N_NODES + 3) / 4, 256, 0, stream>>>(
        (const unsigned*)ego_bf, rowptr, cpack, side);
    dense_kernel<<<(N_NODES + 63) / 64, 256, 0, stream>>>(
        emb, nullptr, side, (const bf16x8*)wpk,
        bsum, bprod,
        out + slot, rn, ego_bf);   // writes normalized slot1 + rn + bf16(unnorm)

    // ---- layer 2
    spmm_csr_kernel<<<(N_NODES + 3) / 4, 256, 0, stream>>>(
        (const unsigned*)ego_bf, rowptr, cpack, side);
    dense_kernel<<<(N_NODES + 63) / 64, 256, 0, stream>>>(
        out + slot, rn, side, (const bf16x8*)wpk + 4096,
        bsum + D, bprod + D,
        out + 2 * slot, nullptr, nullptr);  // writes normalized slot2
}

// Round 6
// 406.410 us; speedup vs baseline: 1.1813x; 1.1813x over previous
//
#include <hip/hip_runtime.h>
#include <hip/hip_bf16.h>

#define N_NODES 100000
#define EDGES   1600000
#define D       128
#define NLAYERS 2
#define NEG_SLOPE 0.01f
#define BK 256                          // rows per bucket (= scan block)
#define NBK ((N_NODES + BK - 1) / BK)   // 391 buckets / scan blocks
#define VAL_SCALE 524288.0f             // 2^19: val in [0,1/16) -> q in [0,32767]
#define VAL_INV   (1.0f / 524288.0f)

typedef __attribute__((ext_vector_type(8))) __bf16 bf16x8;
typedef __attribute__((ext_vector_type(4))) float  f32x4;

__device__ __forceinline__ float bf_lo(unsigned u) { return __uint_as_float(u << 16); }
__device__ __forceinline__ float bf_hi(unsigned u) { return __uint_as_float(u & 0xffff0000u); }

// ---------------- CSR build step 1: row histogram
__global__ void hist_kernel(const int* __restrict__ arow, int* __restrict__ deg) {
    int e = blockIdx.x * 256 + threadIdx.x;
    if (e < EDGES) atomicAdd(&deg[arow[e]], 1);
}

// ---------------- CSR build step 2a: per-block reduce of deg
__global__ __launch_bounds__(256) void reduce_deg_kernel(const int* __restrict__ deg,
                                                         int* __restrict__ bsum) {
    __shared__ int sh[256];
    int t = threadIdx.x, i = blockIdx.x * 256 + t;
    sh[t] = (i < N_NODES) ? deg[i] : 0;
    __syncthreads();
    for (int off = 128; off > 0; off >>= 1) {
        if (t < off) sh[t] += sh[t + off];
        __syncthreads();
    }
    if (t == 0) bsum[blockIdx.x] = sh[0];
}

// ---------------- CSR build step 2b: single-block scan of 391 partials
__global__ __launch_bounds__(512) void scan_partials_kernel(const int* __restrict__ bsum,
                                                            int* __restrict__ boff,
                                                            int* __restrict__ rowptr) {
    __shared__ int sh[512];
    int t = threadIdx.x;
    int v = (t < NBK) ? bsum[t] : 0;
    sh[t] = v;
    __syncthreads();
    for (int off = 1; off < 512; off <<= 1) {
        int u = (t >= off) ? sh[t - off] : 0;
        __syncthreads();
        sh[t] += u;
        __syncthreads();
    }
    if (t < NBK) boff[t] = sh[t] - v;          // exclusive = rowptr[t*BK]
    if (t == 0) rowptr[N_NODES] = sh[NBK - 1]; // total == EDGES
}

// ---------------- CSR build step 2c: block-local scan + offset -> rowptr
__global__ __launch_bounds__(256) void scan_rows_kernel(const int* __restrict__ deg,
                                                        const int* __restrict__ boff,
                                                        int* __restrict__ rowptr) {
    __shared__ int sh[256];
    int t = threadIdx.x, i = blockIdx.x * 256 + t;
    int d = (i < N_NODES) ? deg[i] : 0;
    sh[t] = d;
    __syncthreads();
    for (int off = 1; off < 256; off <<= 1) {
        int u = (t >= off) ? sh[t - off] : 0;
        __syncthreads();
        sh[t] += u;
        __syncthreads();
    }
    if (i < N_NODES) rowptr[i] = boff[blockIdx.x] + sh[t] - d;
}

// ---------------- partition phase A: bin edges by 256-row bucket (u64 packed)
// Per block: count buckets in LDS, reserve region via one global atomic per
// bucket, then write edges grouped by bucket (~10-edge contiguous runs).
__global__ __launch_bounds__(256) void binA_kernel(
    const int*   __restrict__ arow,
    const int*   __restrict__ acol,
    const float* __restrict__ aval,
    int*         __restrict__ gcur,     // per-bucket cursor, init = rowptr[b*BK]
    unsigned long long* __restrict__ binned) {
    __shared__ int cnt[NBK];
    __shared__ int base[NBK];
    for (int b = threadIdx.x; b < NBK; b += 256) cnt[b] = 0;
    __syncthreads();
    int e0 = blockIdx.x * 4096;
    for (int i = threadIdx.x; i < 4096; i += 256) {
        int e = e0 + i;
        if (e < EDGES) atomicAdd(&cnt[arow[e] >> 8], 1);
    }
    __syncthreads();
    for (int b = threadIdx.x; b < NBK; b += 256) {
        int c = cnt[b];
        base[b] = c ? atomicAdd(&gcur[b], c) : 0;
        cnt[b] = 0;
    }
    __syncthreads();
    for (int i = threadIdx.x; i < 4096; i += 256) {
        int e = e0 + i;
        if (e < EDGES) {
            int r = arow[e];
            int b = r >> 8;
            int rank = atomicAdd(&cnt[b], 1);
            int q = (int)(aval[e] * VAL_SCALE);
            if (q > 32767) q = 32767;
            unsigned long long pk =
                ((unsigned long long)(r & 255) << 32) |
                (unsigned long long)(((unsigned)acol[e] << 15) | (unsigned)q);
            binned[base[b] + rank] = pk;
        }
    }
}

// ---------------- partition phase B: within-bucket scatter to final CSR pos.
// One block per bucket; LDS row cursors; writes confined to the bucket's
// contiguous ~16KB cpack range -> ~1x write amplification.
__global__ __launch_bounds__(256) void binB_kernel(
    const int* __restrict__ rowptr,
    const unsigned long long* __restrict__ binned,
    unsigned* __restrict__ cpack) {
    __shared__ int cur[BK];
    int b  = blockIdx.x;
    int r0 = b * BK;
    int rows = N_NODES - r0; if (rows > BK) rows = BK;
    for (int i = threadIdx.x; i < rows; i += 256) cur[i] = rowptr[r0 + i];
    __syncthreads();
    int begin = rowptr[r0];
    int endb  = rowptr[r0 + rows];
    for (int i = begin + threadIdx.x; i < endb; i += 256) {
        unsigned long long pk = binned[i];
        int rl  = (int)(pk >> 32);
        int pos = atomicAdd(&cur[rl], 1);
        cpack[pos] = (unsigned)pk;
    }
}

__global__ void init_gcur_kernel(const int* __restrict__ boff, int* __restrict__ gcur) {
    int b = blockIdx.x * 256 + threadIdx.x;
    if (b < NBK) gcur[b] = boff[b];   // boff[b] == rowptr[b*BK]
}

// ---------------- out slot0 = emb (f32) and ego_bf = bf16(emb), one read pass
__global__ void copy_emb_kernel(const float* __restrict__ emb,
                                float* __restrict__ out0,
                                __bf16* __restrict__ bf) {
    int t = blockIdx.x * 256 + threadIdx.x;   // N*D/8 threads
    if (t >= N_NODES * D / 8) return;
    const float4* p = (const float4*)emb + (size_t)t * 2;
    float4 a = p[0], b = p[1];
    ((float4*)out0)[(size_t)t * 2]     = a;
    ((float4*)out0)[(size_t)t * 2 + 1] = b;
    bf16x8 o;
    o[0] = (__bf16)a.x; o[1] = (__bf16)a.y; o[2] = (__bf16)a.z; o[3] = (__bf16)a.w;
    o[4] = (__bf16)b.x; o[5] = (__bf16)b.y; o[6] = (__bf16)b.z; o[7] = (__bf16)b.w;
    *((bf16x8*)bf + t) = o;
}

// ---------------- SpMM (CSR gather, bf16 ego, packed u32 edges): one wave per row
__global__ __launch_bounds__(256) void spmm_csr_kernel(
    const unsigned* __restrict__ ego_bf,   // N x D bf16 as uint pairs
    const int*      __restrict__ rowptr,
    const unsigned* __restrict__ cpack,
    float*          __restrict__ side) {
    int row  = blockIdx.x * 4 + (threadIdx.x >> 6);
    int lane = threadIdx.x & 63;
    if (row >= N_NODES) return;
    int beg = rowptr[row], end = rowptr[row + 1];
    float accx = 0.f, accy = 0.f;
    int e = beg;
    for (; e + 4 <= end; e += 4) {
        unsigned p0 = cpack[e], p1 = cpack[e + 1], p2 = cpack[e + 2], p3 = cpack[e + 3];
        unsigned u0 = ego_bf[(size_t)(p0 >> 15) * (D / 2) + lane];
        unsigned u1 = ego_bf[(size_t)(p1 >> 15) * (D / 2) + lane];
        unsigned u2 = ego_bf[(size_t)(p2 >> 15) * (D / 2) + lane];
        unsigned u3 = ego_bf[(size_t)(p3 >> 15) * (D / 2) + lane];
        float v0 = (float)(p0 & 0x7fffu) * VAL_INV;
        float v1 = (float)(p1 & 0x7fffu) * VAL_INV;
        float v2 = (float)(p2 & 0x7fffu) * VAL_INV;
        float v3 = (float)(p3 & 0x7fffu) * VAL_INV;
        accx += v0 * bf_lo(u0) + v1 * bf_lo(u1) + v2 * bf_lo(u2) + v3 * bf_lo(u3);
        accy += v0 * bf_hi(u0) + v1 * bf_hi(u1) + v2 * bf_hi(u2) + v3 * bf_hi(u3);
    }
    for (; e < end; e++) {
        unsigned p = cpack[e];
        unsigned u = ego_bf[(size_t)(p >> 15) * (D / 2) + lane];
        float v = (float)(p & 0x7fffu) * VAL_INV;
        accx += v * bf_lo(u);
        accy += v * bf_hi(u);
    }
    *((float2*)(side + (size_t)row * D) + lane) = make_float2(accx, accy);
}

// ---------------- Prepack W (both layers, both mats) into MFMA B-fragment order, bf16.
__global__ void prepack_kernel(const float* __restrict__ wsum,
                               const float* __restrict__ wprod,
                               __bf16*      __restrict__ wpk) {
    int t = blockIdx.x * blockDim.x + threadIdx.x;   // 65536 total
    int j     = t & 7;
    int lane  = (t >> 3) & 63;
    int cf    = (t >> 9) & 7;
    int kc    = (t >> 12) & 3;
    int mat   = (t >> 14) & 1;
    int layer = (t >> 15) & 1;
    int k   = kc * 32 + (lane >> 4) * 8 + j;
    int col = cf * 16 + (lane & 15);
    const float* W = mat ? wprod : wsum;
    wpk[t] = (__bf16)W[((size_t)layer * D + k) * D + col];
}

// ---------------- Fused dense + L2-normalize epilogue.
__global__ __launch_bounds__(256) void dense_kernel(
    const float*  __restrict__ ego,
    const float*  __restrict__ ego_scale,  // nullable: per-row un-normalize factor
    const float*  __restrict__ side,
    const bf16x8* __restrict__ wpk,        // this layer: 2048 sum frags, then 2048 prod
    const float*  __restrict__ bsum,
    const float*  __restrict__ bprod,
    float*        __restrict__ out_norm,
    float*        __restrict__ rn,         // nullable
    __bf16*       __restrict__ out_bf) {   // nullable
    int lane = threadIdx.x & 63;
    int wid  = threadIdx.x >> 6;
    int node_base = blockIdx.x * 64 + wid * 16;
    int arow_node = node_base + (lane & 15);   // A-frag row
    int kgrp = lane >> 4;

    f32x4 acc_s[8], acc_p[8];
#pragma unroll
    for (int i = 0; i < 8; i++) { acc_s[i] = (f32x4)(0.f); acc_p[i] = (f32x4)(0.f); }

    bool avalid = arow_node < N_NODES;
    const float* erow = ego  + (size_t)arow_node * D;
    const float* srow = side + (size_t)arow_node * D;
    float esc = (ego_scale && avalid) ? ego_scale[arow_node] : 1.0f;

#pragma unroll
    for (int kc = 0; kc < 4; kc++) {
        int kbase = kc * 32 + kgrp * 8;
        bf16x8 a_s, a_p;
        if (avalid) {
            float4 e0 = *(const float4*)(erow + kbase);
            float4 e1 = *(const float4*)(erow + kbase + 4);
            float4 s0 = *(const float4*)(srow + kbase);
            float4 s1 = *(const float4*)(srow + kbase + 4);
            float es[8] = {e0.x, e0.y, e0.z, e0.w, e1.x, e1.y, e1.z, e1.w};
            float ss[8] = {s0.x, s0.y, s0.z, s0.w, s1.x, s1.y, s1.z, s1.w};
#pragma unroll
            for (int j = 0; j < 8; j++) {
                float ev = es[j] * esc;
                a_s[j] = (__bf16)(ev + ss[j]);
                a_p[j] = (__bf16)(ev * ss[j]);
            }
        } else {
#pragma unroll
            for (int j = 0; j < 8; j++) { a_s[j] = (__bf16)0.f; a_p[j] = (__bf16)0.f; }
        }
#pragma unroll
        for (int cf = 0; cf < 8; cf++) {
            bf16x8 bs = wpk[(kc * 8 + cf) * 64 + lane];
            bf16x8 bp = wpk[2048 + (kc * 8 + cf) * 64 + lane];
            acc_s[cf] = __builtin_amdgcn_mfma_f32_16x16x32_bf16(a_s, bs, acc_s[cf], 0, 0, 0);
            acc_p[cf] = __builtin_amdgcn_mfma_f32_16x16x32_bf16(a_p, bp, acc_p[cf], 0, 0, 0);
        }
    }

    // epilogue: C/D layout col = lane&15, row = (lane>>4)*4 + reg
    int colb = lane & 15;
    float ssq[4] = {0.f, 0.f, 0.f, 0.f};
#pragma unroll
    for (int cf = 0; cf < 8; cf++) {
        int d = cf * 16 + colb;
        float bsv = bsum[d], bpv = bprod[d];
#pragma unroll
        for (int r = 0; r < 4; r++) {
            float ys = acc_s[cf][r] + bsv;
            float yp = acc_p[cf][r] + bpv;
            ys = ys >= 0.f ? ys : NEG_SLOPE * ys;
            yp = yp >= 0.f ? yp : NEG_SLOPE * yp;
            float y = ys + yp;
            acc_s[cf][r] = y;          // reuse acc_s as y storage
            ssq[r] += y * y;
        }
    }
#pragma unroll
    for (int r = 0; r < 4; r++) {
#pragma unroll
        for (int m = 1; m < 16; m <<= 1) ssq[r] += __shfl_xor(ssq[r], m);
    }
    float nrm[4], inv[4];
#pragma unroll
    for (int r = 0; r < 4; r++) {
        nrm[r] = fmaxf(sqrtf(ssq[r]), 1e-12f);
        inv[r] = 1.0f / nrm[r];
    }
#pragma unroll
    for (int cf = 0; cf < 8; cf++) {
        int d = cf * 16 + colb;
#pragma unroll
        for (int r = 0; r < 4; r++) {
            int node = node_base + kgrp * 4 + r;
            if (node < N_NODES) {
                float y = acc_s[cf][r];
                out_norm[(size_t)node * D + d] = y * inv[r];
                if (out_bf) out_bf[(size_t)node * D + d] = (__bf16)y;
            }
        }
    }
    if (rn && colb == 0) {
#pragma unroll
        for (int r = 0; r < 4; r++) {
            int node = node_base + kgrp * 4 + r;
            if (node < N_NODES) rn[node] = nrm[r];
        }
    }
}

extern "C" void kernel_launch(void* const* d_in, const int* in_sizes, int n_in,
                              void* d_out, int out_size, void* d_ws, size_t ws_size,
                              hipStream_t stream) {
    const float* emb   = (const float*)d_in[0];
    const int*   arow  = (const int*)d_in[1];
    const int*   acol  = (const int*)d_in[2];
    const float* aval  = (const float*)d_in[3];
    const float* wsum  = (const float*)d_in[4];
    const float* bsum  = (const float*)d_in[5];
    const float* wprod = (const float*)d_in[6];
    const float* bprod = (const float*)d_in[7];
    float* out = (float*)d_out;

    const size_t slot = (size_t)N_NODES * D;          // elements per [N,D] slab
    char* ws = (char*)d_ws;
    size_t off = 0;
    float*    side   = (float*)(ws + off); off += slot * 4;                 // 51.2 MB
    __bf16*   wpk    = (__bf16*)(ws + off); off += 65536 * 2;               // 128 KB
    int*      deg    = (int*)(ws + off); off += (size_t)N_NODES * 4;        // 400 KB
    int*      rowptr = (int*)(ws + off); off += ((size_t)N_NODES + 4) * 4;  // 400 KB
    unsigned* cpack  = (unsigned*)(ws + off); off += (size_t)EDGES * 4;     // 6.4 MB
    int*      bsumP  = (int*)(ws + off); off += (size_t)NBK * 4;
    int*      boffP  = (int*)(ws + off); off += (size_t)NBK * 4;
    int*      gcur   = (int*)(ws + off); off += (size_t)NBK * 4;
    float*    rn     = (float*)(ws + off); off += (size_t)N_NODES * 4;      // 400 KB

    // out slot 2 aliasing (all uses stream-ordered strictly before dense-2
    // overwrites slot 2):
    //   first half  : ego_bf (bf16 ego for spmm)    [25.6 MB]
    //   second half : binned u64 edge staging       [12.8 MB of 25.6]
    __bf16* ego_bf = (__bf16*)(out + 2 * slot);
    unsigned long long* binned = (unsigned long long*)((char*)(out + 2 * slot) + slot * 2);

    // ---- CSR build (once, reused by both layers)
    hipMemsetAsync(deg, 0, (size_t)N_NODES * 4, stream);
    hist_kernel<<<(EDGES + 255) / 256, 256, 0, stream>>>(arow, deg);
    reduce_deg_kernel<<<NBK, 256, 0, stream>>>(deg, bsumP);
    scan_partials_kernel<<<1, 512, 0, stream>>>(bsumP, boffP, rowptr);
    scan_rows_kernel<<<NBK, 256, 0, stream>>>(deg, boffP, rowptr);
    init_gcur_kernel<<<(NBK + 255) / 256, 256, 0, stream>>>(boffP, gcur);
    binA_kernel<<<(EDGES + 4095) / 4096, 256, 0, stream>>>(arow, acol, aval, gcur, binned);
    binB_kernel<<<NBK, 256, 0, stream>>>(rowptr, binned, cpack);

    // out slot 0 = embeddings (f32) + bf16 ego for layer-1 spmm, one pass
    copy_emb_kernel<<<(N_NODES * D / 8 + 255) / 256, 256, 0, stream>>>(emb, out, ego_bf);

    prepack_kernel<<<65536 / 256, 256, 0, stream>>>(wsum, wprod, wpk);

    // ---- layer 1
    spmm_csr_kernel<<<(N_NODES + 3) / 4, 256, 0, stream>>>(
        (const unsigned*)ego_bf, rowptr, cpack, side);
    dense_kernel<<<(N_NODES + 63) / 64, 256, 0, stream>>>(
        emb, nullptr, side, (const bf16x8*)wpk,
        bsum, bprod,
        out + slot, rn, ego_bf);   // writes normalized slot1 + rn + bf16(unnorm)

    // ---- layer 2
    spmm_csr_kernel<<<(N_NODES + 3) / 4, 256, 0, stream>>>(
        (const unsigned*)ego_bf, rowptr, cpack, side);
    dense_kernel<<<(N_NODES + 63) / 64, 256, 0, stream>>>(
        out + slot, rn, side, (const bf16x8*)wpk + 4096,
        bsum + D, bprod + D,
        out + 2 * slot, nullptr, nullptr);  // writes normalized slot2
}